// Round 8
// baseline (121.599 us; speedup 1.0000x reference)
//
#include <hip/hip_runtime.h>
#include <hip/hip_cooperative_groups.h>
#include <stdint.h>
#include <stddef.h>

namespace cg = cooperative_groups;

#define B_   16
#define C1_  512
#define HW_  1024
#define CS_  32
#define CE_  496
#define CO_  1008   // C1_ + CE_

typedef __attribute__((ext_vector_type(8))) short short8;
typedef __attribute__((ext_vector_type(4))) short short4v;
typedef __attribute__((ext_vector_type(4))) float f32x4;

__device__ __forceinline__ short f2bf(float f) {
  unsigned u = __builtin_bit_cast(unsigned, f);
  unsigned r = (u + 0x7fffu + ((u >> 16) & 1u)) >> 16;   // RNE
  return (short)(unsigned short)r;
}

__device__ __forceinline__ void gload_lds16(const void* g, void* l) {
  __builtin_amdgcn_global_load_lds(
      (const __attribute__((address_space(1))) unsigned int*)g,
      (__attribute__((address_space(3))) unsigned int*)l, 16, 0, 0);
}

// ---------------- transpose x[b,c,p] f32 -> xT[b,p,c] bf16, fused pool partials
// ---------------- + appended prep blocks (w->bf16, BN fold) ----------------
__global__ __launch_bounds__(256) void transpose_pool(const float* __restrict__ x,
                                                      short* __restrict__ xT,
                                                      float* __restrict__ partial,
                                                      const float* __restrict__ fc_w,
                                                      const float* __restrict__ fc_b,
                                                      const float* __restrict__ bn_gamma,
                                                      const float* __restrict__ bn_beta,
                                                      const float* __restrict__ bn_mean,
                                                      const float* __restrict__ bn_var,
                                                      short* __restrict__ wbf,
                                                      float* __restrict__ bs,
                                                      float* __restrict__ bb) {
  int bid = blockIdx.x;
  int tid = threadIdx.x;
  if (bid >= 2048) {                       // prep tail
    if (bid < 3072) {
      int i = (bid - 2048) * 256 + tid;
      wbf[i] = f2bf(fc_w[i]);
    } else {
      for (int o = tid; o < C1_; o += 256) {
        float s = bn_gamma[o] / sqrtf(bn_var[o] + 1e-5f);
        bs[o] = s;
        bb[o] = (fc_b[o] - bn_mean[o]) * s + bn_beta[o];
      }
    }
    return;
  }
  __shared__ float tile[64][65];
  int b = bid >> 7;            // 128 tiles per batch (8 c-tiles x 16 p-tiles)
  int tt = bid & 127;
  int ct = tt >> 4, pt = tt & 15;
  int c0 = ct * 64, p0 = pt * 64;
  int rr = tid >> 4, lc = tid & 15;
  const float* xb = x + (size_t)b * C1_ * HW_;
#pragma unroll
  for (int it = 0; it < 4; ++it) {
    int c = it * 16 + rr;
    int p4 = lc * 4;
    float4 v = *(const float4*)(xb + (size_t)(c0 + c) * HW_ + p0 + p4);
    tile[c][p4+0] = v.x; tile[c][p4+1] = v.y; tile[c][p4+2] = v.z; tile[c][p4+3] = v.w;
    float g = v.x + v.y + v.z + v.w;
    g += __shfl_down(g, 8, 16);
    g += __shfl_down(g, 4, 16);
    g += __shfl_down(g, 2, 16);
    g += __shfl_down(g, 1, 16);
    if (lc == 0) partial[((size_t)b * 16 + pt) * C1_ + c0 + c] = g;   // unique writer, deterministic
  }
  __syncthreads();
#pragma unroll
  for (int it = 0; it < 4; ++it) {
    int p = it * 16 + rr;
    int c4 = lc * 4;
    short4v o;
    o[0] = f2bf(tile[c4+0][p]);
    o[1] = f2bf(tile[c4+1][p]);
    o[2] = f2bf(tile[c4+2][p]);
    o[3] = f2bf(tile[c4+3][p]);
    *(short4v*)(xT + (size_t)b * HW_ * C1_ + (size_t)(p0 + p) * C1_ + c0 + c4) = o;
  }
}

// ---------------- cooperative selection: fc GEMV -> eva GEMV -> top-32 ----------------
// 128 blocks x 64 threads; per-row arithmetic copied verbatim from the split kernels
// (bit-identical logits => identical top-k). grid.sync() between phases.
__global__ __launch_bounds__(64) void select_coop(
    const float* __restrict__ partial, const float* __restrict__ fc_w,
    const float* __restrict__ bs, const float* __restrict__ bb,
    const float* __restrict__ eva_w, const float* __restrict__ eva_b,
    float* __restrict__ pb, float* __restrict__ logits, int* __restrict__ idx) {
  cg::grid_group grid = cg::this_grid();
  int b = blockIdx.x >> 3, ot = blockIdx.x & 7;
  int tid = threadIdx.x;

  // phase 1: pooled fc row (fused pool reduce, fixed order)
  {
    __shared__ float px[512];
    for (int c = tid; c < 512; c += 64) {
      float s = 0.f;
#pragma unroll
      for (int pt = 0; pt < 16; ++pt) s += partial[((size_t)b * 16 + pt) * C1_ + c];
      px[c] = s * (1.f / 1024.f);
    }
    __syncthreads();
    int o = ot * 64 + tid;
    const float4* wr = (const float4*)(fc_w + (size_t)o * 512);
    float acc = 0.f;
#pragma unroll 8
    for (int q = 0; q < 128; ++q) {
      float4 w = wr[q];
      acc += w.x * px[q*4] + w.y * px[q*4+1] + w.z * px[q*4+2] + w.w * px[q*4+3];
    }
    pb[b * 512 + o] = acc * bs[o] + bb[o];
  }
  grid.sync();

  // phase 2: eva row
  {
    __shared__ float ps[512];
    for (int c = tid; c < 512; c += 64) ps[c] = pb[b * 512 + c];
    __syncthreads();
    int o = ot * 64 + tid;
    const float4* wr = (const float4*)(eva_w + (size_t)o * 512);
    float acc = 0.f;
#pragma unroll 8
    for (int q = 0; q < 128; ++q) {
      float4 w = wr[q];
      acc += w.x * ps[q*4] + w.y * ps[q*4+1] + w.z * ps[q*4+2] + w.w * ps[q*4+3];
    }
    logits[b * 512 + o] = acc + eva_b[o];
  }
  grid.sync();

  // phase 3: top-32 on blocks 0..15 (one wave per batch, desc value / asc index)
  if (blockIdx.x < 16) {
    int bb_ = blockIdx.x, lane = tid;
    float v[8];
    int base = lane * 8;
#pragma unroll
    for (int u = 0; u < 8; ++u) v[u] = logits[bb_ * 512 + base + u];
    for (int it = 0; it < CS_; ++it) {
      float bv = v[0]; int bu = 0;
#pragma unroll
      for (int u = 1; u < 8; ++u) if (v[u] > bv) { bv = v[u]; bu = u; }
      int bi = base + bu;
      for (int off = 32; off; off >>= 1) {
        float ov = __shfl_down(bv, off);
        int   oi = __shfl_down(bi, off);
        if (ov > bv || (ov == bv && oi < bi)) { bv = ov; bi = oi; }
      }
      bi = __shfl(bi, 0);
      if (lane == 0) idx[bb_ * CS_ + it] = bi;
#pragma unroll
      for (int u = 0; u < 8; ++u) if (bi == base + u) v[u] = -3.4e38f;
    }
  }
}

// ---------------- bf16 MFMA GEMM: out_x[b,o,p] = BN(fc_w @ x) ----------------
// 128x128 tile, BK=64, dbuf, T2 XOR-swizzle, direct-store epilogue, XCD-chunked.
__global__ __launch_bounds__(256) void gemm_kernel(const short* __restrict__ W,
                                                   const short* __restrict__ XT,
                                                   const float* __restrict__ bs,
                                                   const float* __restrict__ bb,
                                                   float* __restrict__ out) {
  __shared__ char smem[65536];   // A0|A1|B0|B1 = 4 x 16 KB
  int bid = (blockIdx.x & 7) * 64 + (blockIdx.x >> 3);   // XCD-chunked
  int b = bid >> 5;
  int t = bid & 31;
  int mt = t & 3, ntile = t >> 2;
  int m0 = mt * 128, n0 = ntile * 128;
  const short* Ag = W + (size_t)m0 * 512;
  const short* Bg = XT + (size_t)b * HW_ * 512 + (size_t)n0 * 512;
  int tid = threadIdx.x;
  int lane = tid & 63, wave = tid >> 6;
  int wr = wave >> 1, wc = wave & 1;
  int mrow = wr * 64, ncol = wc * 64;
  int lrow = lane & 15;
  int swz = (lrow & 7) << 4;                 // row-XOR swizzle

  f32x4 acc[4][4];
#pragma unroll
  for (int i = 0; i < 4; ++i)
#pragma unroll
    for (int j = 0; j < 4; ++j) acc[i][j] = (f32x4){0.f, 0.f, 0.f, 0.f};

  // staging: LDS linear dest, inverse-swizzled global source (involution, 16B granular)
#define STAGE(dstbase, k0)                                                      \
  {                                                                             \
    _Pragma("unroll")                                                           \
    for (int it_ = 0; it_ < 4; ++it_) {                                         \
      int s_ = it_ * 256 + tid;                                                 \
      int L_ = s_ * 16;                                                         \
      int row_ = L_ >> 7;                                                       \
      int w_ = L_ & 127;                                                        \
      int srcs_ = (w_ ^ ((row_ & 7) << 4)) >> 1;                                \
      gload_lds16(Ag + (size_t)row_ * 512 + (k0) + srcs_,                       \
                  smem + (dstbase) + L_);                                       \
      gload_lds16(Bg + (size_t)row_ * 512 + (k0) + srcs_,                       \
                  smem + 32768 + (dstbase) + L_);                               \
    }                                                                           \
  }

  STAGE(0, 0)
  asm volatile("s_waitcnt vmcnt(0)" ::: "memory");
  __syncthreads();

  int cur = 0;
  for (int kt = 0; kt < 8; ++kt) {
    if (kt < 7) STAGE((cur ^ 1) * 16384, (kt + 1) * 64)
    const char* Ab = smem + cur * 16384;
    const char* Bb = smem + 32768 + cur * 16384;
#pragma unroll
    for (int kk = 0; kk < 2; ++kk) {
      int kb = (kk * 64 + (lane >> 4) * 16) ^ swz;
      short8 af[4], bfv[4];
#pragma unroll
      for (int f = 0; f < 4; ++f) {
        af[f]  = *(const short8*)(Ab + (mrow + f * 16 + lrow) * 128 + kb);
        bfv[f] = *(const short8*)(Bb + (ncol + f * 16 + lrow) * 128 + kb);
      }
#pragma unroll
      for (int mf = 0; mf < 4; ++mf)
#pragma unroll
        for (int nf = 0; nf < 4; ++nf)
          acc[mf][nf] = __builtin_amdgcn_mfma_f32_16x16x32_bf16(af[mf], bfv[nf], acc[mf][nf], 0, 0, 0);
    }
    asm volatile("s_waitcnt vmcnt(0)" ::: "memory");
    __syncthreads();
    cur ^= 1;
  }

  // epilogue: direct stores
  float* outb = out + (size_t)b * CO_ * HW_;
#pragma unroll
  for (int mf = 0; mf < 4; ++mf) {
#pragma unroll
    for (int j = 0; j < 4; ++j) {
      int o = m0 + mrow + mf * 16 + (lane >> 4) * 4 + j;   // C/D: row=(lane>>4)*4+reg
      float s = bs[o], bv = bb[o];
#pragma unroll
      for (int nf = 0; nf < 4; ++nf) {
        int p = n0 + ncol + nf * 16 + lrow;                // C/D: col=lane&15
        outb[(size_t)o * HW_ + p] = acc[mf][nf][j] * s + bv;
      }
    }
  }
#undef STAGE
}

// ---------------- hada: fused per-pair stats + normalized product write ----------------
__global__ __launch_bounds__(256) void hada_kernel(
    const int* __restrict__ idx, const float* __restrict__ bn_gamma,
    const float* __restrict__ bn_beta, float* __restrict__ out) {
  int e = blockIdx.x, tid = threadIdx.x;
  int lane = tid & 63, wave = tid >> 6;
  // pair (i<j) from linear index e
  int i = 0, rem = e;
  while (rem >= 31 - i) { rem -= 31 - i; ++i; }
  int j = i + 1 + rem;

  __shared__ int chi[16], chj[16];
  if (tid < 16) chi[tid] = idx[tid * CS_ + i];
  else if (tid < 32) chj[tid - 16] = idx[(tid - 16) * CS_ + j];
  __syncthreads();

  f32x4 p[16];
  float s = 0.f, s2 = 0.f;
#pragma unroll
  for (int b = 0; b < 16; ++b) {
    const float4* xi = (const float4*)(out + ((size_t)b * CO_ + chi[b]) * HW_);
    const float4* xj = (const float4*)(out + ((size_t)b * CO_ + chj[b]) * HW_);
    float4 a = xi[tid], c = xj[tid];
    p[b][0] = a.x * c.x; p[b][1] = a.y * c.y; p[b][2] = a.z * c.z; p[b][3] = a.w * c.w;
    s  += p[b][0] + p[b][1] + p[b][2] + p[b][3];
    s2 += p[b][0]*p[b][0] + p[b][1]*p[b][1] + p[b][2]*p[b][2] + p[b][3]*p[b][3];
  }
  for (int off = 32; off; off >>= 1) { s += __shfl_down(s, off); s2 += __shfl_down(s2, off); }
  __shared__ float red[8];
  if (lane == 0) { red[wave] = s; red[4 + wave] = s2; }
  __syncthreads();
  float S  = red[0] + red[1] + red[2] + red[3];
  float S2 = red[4] + red[5] + red[6] + red[7];
  float mean = S * (1.f / 16384.f);
  float var  = S2 * (1.f / 16384.f) - mean * mean;
  float sc = (bn_gamma[i] * bn_gamma[j]) / sqrtf(var + 1e-5f);
  float bi_ = bn_beta[i] * bn_beta[j] - mean * sc;

#pragma unroll
  for (int b = 0; b < 16; ++b) {
    float4 r;
    r.x = p[b][0] * sc + bi_;
    r.y = p[b][1] * sc + bi_;
    r.z = p[b][2] * sc + bi_;
    r.w = p[b][3] * sc + bi_;
    ((float4*)(out + ((size_t)b * CO_ + C1_ + e) * HW_))[tid] = r;
  }
}

// ---------------- workspace layout (bytes) ----------------
#define XT_OFF     ((size_t)0)          // 16*1024*512*2 = 16777216
#define WBF_OFF    ((size_t)16777216)   // 524288
#define PART_OFF   ((size_t)17301504)   // 524288
#define PB_OFF     ((size_t)17825792)   // 32768
#define LOG_OFF    ((size_t)17858560)   // 32768
#define IDX_OFF    ((size_t)17891328)   // 2048
#define BS_OFF     ((size_t)17893376)   // 2048
#define BB_OFF     ((size_t)17895424)   // 2048

extern "C" void kernel_launch(void* const* d_in, const int* in_sizes, int n_in,
                              void* d_out, int out_size, void* d_ws, size_t ws_size,
                              hipStream_t stream) {
  const float* x        = (const float*)d_in[0];
  const float* fc_w     = (const float*)d_in[1];
  const float* fc_b     = (const float*)d_in[2];
  const float* bn_gamma = (const float*)d_in[3];
  const float* bn_beta  = (const float*)d_in[4];
  const float* bn_mean  = (const float*)d_in[5];
  const float* bn_var   = (const float*)d_in[6];
  const float* eva_w    = (const float*)d_in[7];
  const float* eva_b    = (const float*)d_in[8];
  float* out = (float*)d_out;
  char* ws = (char*)d_ws;

  short* xT      = (short*)(ws + XT_OFF);
  short* wbf     = (short*)(ws + WBF_OFF);
  float* partial = (float*)(ws + PART_OFF);
  float* pb      = (float*)(ws + PB_OFF);
  float* logits  = (float*)(ws + LOG_OFF);
  int*   idx     = (int*)(ws + IDX_OFF);
  float* bs      = (float*)(ws + BS_OFF);
  float* bb      = (float*)(ws + BB_OFF);

  hipLaunchKernelGGL(transpose_pool, dim3(3073), dim3(256), 0, stream,
                     x, xT, partial, fc_w, fc_b, bn_gamma, bn_beta, bn_mean, bn_var,
                     wbf, bs, bb);

  {
    void* args[9] = {(void*)&partial, (void*)&fc_w, (void*)&bs, (void*)&bb,
                     (void*)&eva_w, (void*)&eva_b, (void*)&pb, (void*)&logits,
                     (void*)&idx};
    hipLaunchCooperativeKernel((const void*)select_coop, dim3(128), dim3(64),
                               args, 0, stream);
  }

  hipLaunchKernelGGL(gemm_kernel, dim3(512), dim3(256), 0, stream, wbf, xT, bs, bb, out);
  hipLaunchKernelGGL(hada_kernel, dim3(CE_), dim3(256), 0, stream,
                     idx, bn_gamma, bn_beta, out);
}

// Round 9
// 90.110 us; speedup vs baseline: 1.3495x; 1.3495x over previous
//
#include <hip/hip_runtime.h>
#include <stdint.h>
#include <stddef.h>

#define B_   16
#define C1_  512
#define HW_  1024
#define CS_  32
#define CE_  496
#define CO_  1008   // C1_ + CE_

typedef __attribute__((ext_vector_type(8))) short short8;
typedef __attribute__((ext_vector_type(4))) short short4v;
typedef __attribute__((ext_vector_type(4))) float f32x4;

__device__ __forceinline__ short f2bf(float f) {
  unsigned u = __builtin_bit_cast(unsigned, f);
  unsigned r = (u + 0x7fffu + ((u >> 16) & 1u)) >> 16;   // RNE
  return (short)(unsigned short)r;
}

__device__ __forceinline__ void gload_lds16(const void* g, void* l) {
  __builtin_amdgcn_global_load_lds(
      (const __attribute__((address_space(1))) unsigned int*)g,
      (__attribute__((address_space(3))) unsigned int*)l, 16, 0, 0);
}

// ---------------- transpose x[b,c,p] f32 -> xT[b,p,c] bf16, fused pool partials
// ---------------- + appended prep blocks (w->bf16, BN fold) ----------------
__global__ __launch_bounds__(256) void transpose_pool(const float* __restrict__ x,
                                                      short* __restrict__ xT,
                                                      float* __restrict__ partial,
                                                      const float* __restrict__ fc_w,
                                                      const float* __restrict__ fc_b,
                                                      const float* __restrict__ bn_gamma,
                                                      const float* __restrict__ bn_beta,
                                                      const float* __restrict__ bn_mean,
                                                      const float* __restrict__ bn_var,
                                                      short* __restrict__ wbf,
                                                      float* __restrict__ bs,
                                                      float* __restrict__ bb) {
  int bid = blockIdx.x;
  int tid = threadIdx.x;
  if (bid >= 2048) {                       // prep tail
    if (bid < 3072) {
      int i = (bid - 2048) * 256 + tid;
      wbf[i] = f2bf(fc_w[i]);
    } else {
      for (int o = tid; o < C1_; o += 256) {
        float s = bn_gamma[o] / sqrtf(bn_var[o] + 1e-5f);
        bs[o] = s;
        bb[o] = (fc_b[o] - bn_mean[o]) * s + bn_beta[o];
      }
    }
    return;
  }
  __shared__ float tile[64][65];
  int b = bid >> 7;            // 128 tiles per batch (8 c-tiles x 16 p-tiles)
  int tt = bid & 127;
  int ct = tt >> 4, pt = tt & 15;
  int c0 = ct * 64, p0 = pt * 64;
  int rr = tid >> 4, lc = tid & 15;
  const float* xb = x + (size_t)b * C1_ * HW_;
#pragma unroll
  for (int it = 0; it < 4; ++it) {
    int c = it * 16 + rr;
    int p4 = lc * 4;
    float4 v = *(const float4*)(xb + (size_t)(c0 + c) * HW_ + p0 + p4);
    tile[c][p4+0] = v.x; tile[c][p4+1] = v.y; tile[c][p4+2] = v.z; tile[c][p4+3] = v.w;
    float g = v.x + v.y + v.z + v.w;
    g += __shfl_down(g, 8, 16);
    g += __shfl_down(g, 4, 16);
    g += __shfl_down(g, 2, 16);
    g += __shfl_down(g, 1, 16);
    if (lc == 0) partial[((size_t)b * 16 + pt) * C1_ + c0 + c] = g;   // unique writer, deterministic
  }
  __syncthreads();
#pragma unroll
  for (int it = 0; it < 4; ++it) {
    int p = it * 16 + rr;
    int c4 = lc * 4;
    short4v o;
    o[0] = f2bf(tile[c4+0][p]);
    o[1] = f2bf(tile[c4+1][p]);
    o[2] = f2bf(tile[c4+2][p]);
    o[3] = f2bf(tile[c4+3][p]);
    *(short4v*)(xT + (size_t)b * HW_ * C1_ + (size_t)(p0 + p) * C1_ + c0 + c4) = o;
  }
}

// ---------------- logits GEMV 1 (pool reduce fused): pb = BN(fc_w @ pooled/1024) ----------------
__global__ __launch_bounds__(64) void fc_pool_kernel(
    const float* __restrict__ partial, const float* __restrict__ fc_w,
    const float* __restrict__ bs, const float* __restrict__ bb,
    float* __restrict__ pb) {
  int b = blockIdx.x >> 3, ot = blockIdx.x & 7;
  int tid = threadIdx.x;
  __shared__ float px[512];
  for (int c = tid; c < 512; c += 64) {
    float s = 0.f;
#pragma unroll
    for (int pt = 0; pt < 16; ++pt) s += partial[((size_t)b * 16 + pt) * C1_ + c];
    px[c] = s * (1.f / 1024.f);
  }
  __syncthreads();
  int o = ot * 64 + tid;
  const float4* wr = (const float4*)(fc_w + (size_t)o * 512);
  float acc = 0.f;
#pragma unroll 8
  for (int q = 0; q < 128; ++q) {
    float4 w = wr[q];
    acc += w.x * px[q*4] + w.y * px[q*4+1] + w.z * px[q*4+2] + w.w * px[q*4+3];
  }
  pb[b * 512 + o] = acc * bs[o] + bb[o];
}

// ---------------- logits GEMV 2: logits = eva_w @ pb + eva_b ----------------
__global__ __launch_bounds__(64) void eva_kernel(
    const float* __restrict__ pb, const float* __restrict__ eva_w,
    const float* __restrict__ eva_b, float* __restrict__ logits) {
  int b = blockIdx.x >> 3, ot = blockIdx.x & 7;
  int tid = threadIdx.x;
  __shared__ float ps[512];
  for (int c = tid; c < 512; c += 64) ps[c] = pb[b * 512 + c];
  __syncthreads();
  int o = ot * 64 + tid;
  const float4* wr = (const float4*)(eva_w + (size_t)o * 512);
  float acc = 0.f;
#pragma unroll 8
  for (int q = 0; q < 128; ++q) {
    float4 w = wr[q];
    acc += w.x * ps[q*4] + w.y * ps[q*4+1] + w.z * ps[q*4+2] + w.w * ps[q*4+3];
  }
  logits[b * 512 + o] = acc + eva_b[o];
}

// ---------------- exact top-32, wave-synchronous (desc value, asc index tiebreak) ----------------
__global__ __launch_bounds__(64) void topk_kernel(const float* __restrict__ logits,
                                                  int* __restrict__ idx) {
  int b = blockIdx.x, lane = threadIdx.x;
  float v[8];
  int base = lane * 8;
#pragma unroll
  for (int u = 0; u < 8; ++u) v[u] = logits[b * 512 + base + u];
  for (int it = 0; it < CS_; ++it) {
    float bv = v[0]; int bu = 0;
#pragma unroll
    for (int u = 1; u < 8; ++u) if (v[u] > bv) { bv = v[u]; bu = u; }
    int bi = base + bu;
    for (int off = 32; off; off >>= 1) {
      float ov = __shfl_down(bv, off);
      int   oi = __shfl_down(bi, off);
      if (ov > bv || (ov == bv && oi < bi)) { bv = ov; bi = oi; }
    }
    bi = __shfl(bi, 0);
    if (lane == 0) idx[b * CS_ + it] = bi;
#pragma unroll
    for (int u = 0; u < 8; ++u) if (bi == base + u) v[u] = -3.4e38f;
  }
}

// ---------------- bf16 MFMA GEMM: out_x[b,o,p] = BN(fc_w @ x) ----------------
// 128x128 tile, BK=64, dbuf, T2 XOR-swizzle, direct-store epilogue, XCD-chunked.
__global__ __launch_bounds__(256) void gemm_kernel(const short* __restrict__ W,
                                                   const short* __restrict__ XT,
                                                   const float* __restrict__ bs,
                                                   const float* __restrict__ bb,
                                                   float* __restrict__ out) {
  __shared__ char smem[65536];   // A0|A1|B0|B1 = 4 x 16 KB
  int bid = (blockIdx.x & 7) * 64 + (blockIdx.x >> 3);   // XCD-chunked
  int b = bid >> 5;
  int t = bid & 31;
  int mt = t & 3, ntile = t >> 2;
  int m0 = mt * 128, n0 = ntile * 128;
  const short* Ag = W + (size_t)m0 * 512;
  const short* Bg = XT + (size_t)b * HW_ * 512 + (size_t)n0 * 512;
  int tid = threadIdx.x;
  int lane = tid & 63, wave = tid >> 6;
  int wr = wave >> 1, wc = wave & 1;
  int mrow = wr * 64, ncol = wc * 64;
  int lrow = lane & 15;
  int swz = (lrow & 7) << 4;                 // row-XOR swizzle

  f32x4 acc[4][4];
#pragma unroll
  for (int i = 0; i < 4; ++i)
#pragma unroll
    for (int j = 0; j < 4; ++j) acc[i][j] = (f32x4){0.f, 0.f, 0.f, 0.f};

  // staging: LDS linear dest, inverse-swizzled global source (involution, 16B granular)
#define STAGE(dstbase, k0)                                                      \
  {                                                                             \
    _Pragma("unroll")                                                           \
    for (int it_ = 0; it_ < 4; ++it_) {                                         \
      int s_ = it_ * 256 + tid;                                                 \
      int L_ = s_ * 16;                                                         \
      int row_ = L_ >> 7;                                                       \
      int w_ = L_ & 127;                                                        \
      int srcs_ = (w_ ^ ((row_ & 7) << 4)) >> 1;                                \
      gload_lds16(Ag + (size_t)row_ * 512 + (k0) + srcs_,                       \
                  smem + (dstbase) + L_);                                       \
      gload_lds16(Bg + (size_t)row_ * 512 + (k0) + srcs_,                       \
                  smem + 32768 + (dstbase) + L_);                               \
    }                                                                           \
  }

  STAGE(0, 0)
  asm volatile("s_waitcnt vmcnt(0)" ::: "memory");
  __syncthreads();

  int cur = 0;
  for (int kt = 0; kt < 8; ++kt) {
    if (kt < 7) STAGE((cur ^ 1) * 16384, (kt + 1) * 64)
    const char* Ab = smem + cur * 16384;
    const char* Bb = smem + 32768 + cur * 16384;
#pragma unroll
    for (int kk = 0; kk < 2; ++kk) {
      int kb = (kk * 64 + (lane >> 4) * 16) ^ swz;
      short8 af[4], bfv[4];
#pragma unroll
      for (int f = 0; f < 4; ++f) {
        af[f]  = *(const short8*)(Ab + (mrow + f * 16 + lrow) * 128 + kb);
        bfv[f] = *(const short8*)(Bb + (ncol + f * 16 + lrow) * 128 + kb);
      }
#pragma unroll
      for (int mf = 0; mf < 4; ++mf)
#pragma unroll
        for (int nf = 0; nf < 4; ++nf)
          acc[mf][nf] = __builtin_amdgcn_mfma_f32_16x16x32_bf16(af[mf], bfv[nf], acc[mf][nf], 0, 0, 0);
    }
    asm volatile("s_waitcnt vmcnt(0)" ::: "memory");
    __syncthreads();
    cur ^= 1;
  }

  // epilogue: direct stores
  float* outb = out + (size_t)b * CO_ * HW_;
#pragma unroll
  for (int mf = 0; mf < 4; ++mf) {
#pragma unroll
    for (int j = 0; j < 4; ++j) {
      int o = m0 + mrow + mf * 16 + (lane >> 4) * 4 + j;   // C/D: row=(lane>>4)*4+reg
      float s = bs[o], bv = bb[o];
#pragma unroll
      for (int nf = 0; nf < 4; ++nf) {
        int p = n0 + ncol + nf * 16 + lrow;                // C/D: col=lane&15
        outb[(size_t)o * HW_ + p] = acc[mf][nf][j] * s + bv;
      }
    }
  }
#undef STAGE
}

// ---------------- hada: fused per-pair stats + normalized product write ----------------
__global__ __launch_bounds__(256) void hada_kernel(
    const int* __restrict__ idx, const float* __restrict__ bn_gamma,
    const float* __restrict__ bn_beta, float* __restrict__ out) {
  int e = blockIdx.x, tid = threadIdx.x;
  int lane = tid & 63, wave = tid >> 6;
  // pair (i<j) from linear index e
  int i = 0, rem = e;
  while (rem >= 31 - i) { rem -= 31 - i; ++i; }
  int j = i + 1 + rem;

  __shared__ int chi[16], chj[16];
  if (tid < 16) chi[tid] = idx[tid * CS_ + i];
  else if (tid < 32) chj[tid - 16] = idx[(tid - 16) * CS_ + j];
  __syncthreads();

  f32x4 p[16];
  float s = 0.f, s2 = 0.f;
#pragma unroll
  for (int b = 0; b < 16; ++b) {
    const float4* xi = (const float4*)(out + ((size_t)b * CO_ + chi[b]) * HW_);
    const float4* xj = (const float4*)(out + ((size_t)b * CO_ + chj[b]) * HW_);
    float4 a = xi[tid], c = xj[tid];
    p[b][0] = a.x * c.x; p[b][1] = a.y * c.y; p[b][2] = a.z * c.z; p[b][3] = a.w * c.w;
    s  += p[b][0] + p[b][1] + p[b][2] + p[b][3];
    s2 += p[b][0]*p[b][0] + p[b][1]*p[b][1] + p[b][2]*p[b][2] + p[b][3]*p[b][3];
  }
  for (int off = 32; off; off >>= 1) { s += __shfl_down(s, off); s2 += __shfl_down(s2, off); }
  __shared__ float red[8];
  if (lane == 0) { red[wave] = s; red[4 + wave] = s2; }
  __syncthreads();
  float S  = red[0] + red[1] + red[2] + red[3];
  float S2 = red[4] + red[5] + red[6] + red[7];
  float mean = S * (1.f / 16384.f);
  float var  = S2 * (1.f / 16384.f) - mean * mean;
  float sc = (bn_gamma[i] * bn_gamma[j]) / sqrtf(var + 1e-5f);
  float bi_ = bn_beta[i] * bn_beta[j] - mean * sc;

#pragma unroll
  for (int b = 0; b < 16; ++b) {
    float4 r;
    r.x = p[b][0] * sc + bi_;
    r.y = p[b][1] * sc + bi_;
    r.z = p[b][2] * sc + bi_;
    r.w = p[b][3] * sc + bi_;
    ((float4*)(out + ((size_t)b * CO_ + C1_ + e) * HW_))[tid] = r;
  }
}

// ---------------- workspace layout (bytes) ----------------
#define XT_OFF     ((size_t)0)          // 16*1024*512*2 = 16777216
#define WBF_OFF    ((size_t)16777216)   // 524288
#define PART_OFF   ((size_t)17301504)   // 524288
#define PB_OFF     ((size_t)17825792)   // 32768
#define LOG_OFF    ((size_t)17858560)   // 32768
#define IDX_OFF    ((size_t)17891328)   // 2048
#define BS_OFF     ((size_t)17893376)   // 2048
#define BB_OFF     ((size_t)17895424)   // 2048

extern "C" void kernel_launch(void* const* d_in, const int* in_sizes, int n_in,
                              void* d_out, int out_size, void* d_ws, size_t ws_size,
                              hipStream_t stream) {
  const float* x        = (const float*)d_in[0];
  const float* fc_w     = (const float*)d_in[1];
  const float* fc_b     = (const float*)d_in[2];
  const float* bn_gamma = (const float*)d_in[3];
  const float* bn_beta  = (const float*)d_in[4];
  const float* bn_mean  = (const float*)d_in[5];
  const float* bn_var   = (const float*)d_in[6];
  const float* eva_w    = (const float*)d_in[7];
  const float* eva_b    = (const float*)d_in[8];
  float* out = (float*)d_out;
  char* ws = (char*)d_ws;

  short* xT      = (short*)(ws + XT_OFF);
  short* wbf     = (short*)(ws + WBF_OFF);
  float* partial = (float*)(ws + PART_OFF);
  float* pb      = (float*)(ws + PB_OFF);
  float* logits  = (float*)(ws + LOG_OFF);
  int*   idx     = (int*)(ws + IDX_OFF);
  float* bs      = (float*)(ws + BS_OFF);
  float* bb      = (float*)(ws + BB_OFF);

  hipLaunchKernelGGL(transpose_pool, dim3(3073), dim3(256), 0, stream,
                     x, xT, partial, fc_w, fc_b, bn_gamma, bn_beta, bn_mean, bn_var,
                     wbf, bs, bb);
  hipLaunchKernelGGL(fc_pool_kernel, dim3(128), dim3(64), 0, stream,
                     partial, fc_w, bs, bb, pb);
  hipLaunchKernelGGL(eva_kernel, dim3(128), dim3(64), 0, stream,
                     pb, eva_w, eva_b, logits);
  hipLaunchKernelGGL(topk_kernel, dim3(16), dim3(64), 0, stream, logits, idx);
  hipLaunchKernelGGL(gemm_kernel, dim3(512), dim3(256), 0, stream, wbf, xT, bs, bb, out);
  hipLaunchKernelGGL(hada_kernel, dim3(CE_), dim3(256), 0, stream,
                     idx, bn_gamma, bn_beta, out);
}

// Round 10
// 83.443 us; speedup vs baseline: 1.4573x; 1.0799x over previous
//
#include <hip/hip_runtime.h>
#include <stdint.h>
#include <stddef.h>

#define B_   16
#define C1_  512
#define HW_  1024
#define CS_  32
#define CE_  496
#define CO_  1008   // C1_ + CE_

typedef __attribute__((ext_vector_type(8))) short short8;
typedef __attribute__((ext_vector_type(4))) short short4v;
typedef __attribute__((ext_vector_type(4))) float f32x4;

__device__ __forceinline__ short f2bf(float f) {
  unsigned u = __builtin_bit_cast(unsigned, f);
  unsigned r = (u + 0x7fffu + ((u >> 16) & 1u)) >> 16;   // RNE
  return (short)(unsigned short)r;
}

__device__ __forceinline__ void gload_lds16(const void* g, void* l) {
  __builtin_amdgcn_global_load_lds(
      (const __attribute__((address_space(1))) unsigned int*)g,
      (__attribute__((address_space(3))) unsigned int*)l, 16, 0, 0);
}

// ---------------- transpose x[b,c,p] f32 -> xT[b,p,c] bf16, fused pool partials
// ---------------- + appended prep blocks (w->bf16, BN fold) ----------------
__global__ __launch_bounds__(256) void transpose_pool(const float* __restrict__ x,
                                                      short* __restrict__ xT,
                                                      float* __restrict__ partial,
                                                      const float* __restrict__ fc_w,
                                                      const float* __restrict__ fc_b,
                                                      const float* __restrict__ bn_gamma,
                                                      const float* __restrict__ bn_beta,
                                                      const float* __restrict__ bn_mean,
                                                      const float* __restrict__ bn_var,
                                                      short* __restrict__ wbf,
                                                      float* __restrict__ bs,
                                                      float* __restrict__ bb) {
  int bid = blockIdx.x;
  int tid = threadIdx.x;
  if (bid >= 2048) {                       // prep tail
    if (bid < 3072) {
      int i = (bid - 2048) * 256 + tid;
      wbf[i] = f2bf(fc_w[i]);
    } else {
      for (int o = tid; o < C1_; o += 256) {
        float s = bn_gamma[o] / sqrtf(bn_var[o] + 1e-5f);
        bs[o] = s;
        bb[o] = (fc_b[o] - bn_mean[o]) * s + bn_beta[o];
      }
    }
    return;
  }
  __shared__ float tile[64][65];
  int b = bid >> 7;            // 128 tiles per batch (8 c-tiles x 16 p-tiles)
  int tt = bid & 127;
  int ct = tt >> 4, pt = tt & 15;
  int c0 = ct * 64, p0 = pt * 64;
  int rr = tid >> 4, lc = tid & 15;
  const float* xb = x + (size_t)b * C1_ * HW_;
#pragma unroll
  for (int it = 0; it < 4; ++it) {
    int c = it * 16 + rr;
    int p4 = lc * 4;
    float4 v = *(const float4*)(xb + (size_t)(c0 + c) * HW_ + p0 + p4);
    tile[c][p4+0] = v.x; tile[c][p4+1] = v.y; tile[c][p4+2] = v.z; tile[c][p4+3] = v.w;
    float g = v.x + v.y + v.z + v.w;
    g += __shfl_down(g, 8, 16);
    g += __shfl_down(g, 4, 16);
    g += __shfl_down(g, 2, 16);
    g += __shfl_down(g, 1, 16);
    if (lc == 0) partial[((size_t)b * 16 + pt) * C1_ + c0 + c] = g;   // unique writer, deterministic
  }
  __syncthreads();
#pragma unroll
  for (int it = 0; it < 4; ++it) {
    int p = it * 16 + rr;
    int c4 = lc * 4;
    short4v o;
    o[0] = f2bf(tile[c4+0][p]);
    o[1] = f2bf(tile[c4+1][p]);
    o[2] = f2bf(tile[c4+2][p]);
    o[3] = f2bf(tile[c4+3][p]);
    *(short4v*)(xT + (size_t)b * HW_ * C1_ + (size_t)(p0 + p) * C1_ + c0 + c4) = o;
  }
}

// ---------------- logits GEMV 2: logits = eva_w @ pb + eva_b ----------------
__global__ __launch_bounds__(64) void eva_kernel(
    const float* __restrict__ pb, const float* __restrict__ eva_w,
    const float* __restrict__ eva_b, float* __restrict__ logits) {
  int b = blockIdx.x >> 3, ot = blockIdx.x & 7;
  int tid = threadIdx.x;
  __shared__ float ps[512];
  for (int c = tid; c < 512; c += 64) ps[c] = pb[b * 512 + c];
  __syncthreads();
  int o = ot * 64 + tid;
  const float4* wr = (const float4*)(eva_w + (size_t)o * 512);
  float acc = 0.f;
#pragma unroll 8
  for (int q = 0; q < 128; ++q) {
    float4 w = wr[q];
    acc += w.x * ps[q*4] + w.y * ps[q*4+1] + w.z * ps[q*4+2] + w.w * ps[q*4+3];
  }
  logits[b * 512 + o] = acc + eva_b[o];
}

// ---------------- exact top-32, wave-synchronous (desc value, asc index tiebreak) ----------------
__global__ __launch_bounds__(64) void topk_kernel(const float* __restrict__ logits,
                                                  int* __restrict__ idx) {
  int b = blockIdx.x, lane = threadIdx.x;
  float v[8];
  int base = lane * 8;
#pragma unroll
  for (int u = 0; u < 8; ++u) v[u] = logits[b * 512 + base + u];
  for (int it = 0; it < CS_; ++it) {
    float bv = v[0]; int bu = 0;
#pragma unroll
    for (int u = 1; u < 8; ++u) if (v[u] > bv) { bv = v[u]; bu = u; }
    int bi = base + bu;
    for (int off = 32; off; off >>= 1) {
      float ov = __shfl_down(bv, off);
      int   oi = __shfl_down(bi, off);
      if (ov > bv || (ov == bv && oi < bi)) { bv = ov; bi = oi; }
    }
    bi = __shfl(bi, 0);
    if (lane == 0) idx[b * CS_ + it] = bi;
#pragma unroll
    for (int u = 0; u < 8; ++u) if (bi == base + u) v[u] = -3.4e38f;
  }
}

// ---------------- bf16 MFMA GEMM + fc_pool tail ----------------
// gemm blocks 0..511: 128x128 tile, BK=32, 4-buffer counted-vmcnt pipeline
// (prefetch depth 3, raw s_barrier, T2 swizzle per rule 21), direct epilogue.
// blocks 512..639: fc_pool GEMV (pb = BN(fc_w @ pooled/1024)), arithmetic
// identical to the old fc_pool_kernel (bit-identical pb).
__global__ __launch_bounds__(256) void gemm_kernel(const short* __restrict__ W,
                                                   const short* __restrict__ XT,
                                                   const float* __restrict__ bs,
                                                   const float* __restrict__ bb,
                                                   float* __restrict__ out,
                                                   const float* __restrict__ partial,
                                                   const float* __restrict__ fc_w,
                                                   float* __restrict__ pb) {
  __shared__ char smem[65536];   // A: 4x8KB @0, B: 4x8KB @32768
  int tid = threadIdx.x;

  if (blockIdx.x >= 512) {       // ---- fc_pool tail ----
    int bid2 = blockIdx.x - 512; // 0..127 -> but grid is 640 so 0..127? grid=640 => 0..127 no: 640-512=128
    int b = bid2 >> 3, ot = bid2 & 7;
    float* px = (float*)smem;
    for (int c = tid; c < 512; c += 256) {
      float s = 0.f;
#pragma unroll
      for (int pt = 0; pt < 16; ++pt) s += partial[((size_t)b * 16 + pt) * C1_ + c];
      px[c] = s * (1.f / 1024.f);
    }
    __syncthreads();
    if (tid < 64) {
      int o = ot * 64 + tid;
      const float4* wr = (const float4*)(fc_w + (size_t)o * 512);
      float acc = 0.f;
#pragma unroll 8
      for (int q = 0; q < 128; ++q) {
        float4 w = wr[q];
        acc += w.x * px[q*4] + w.y * px[q*4+1] + w.z * px[q*4+2] + w.w * px[q*4+3];
      }
      pb[b * 512 + o] = acc * bs[o] + bb[o];
    }
    return;
  }

  int bid = (blockIdx.x & 7) * 64 + (blockIdx.x >> 3);   // XCD-chunked over 512
  int b = bid >> 5;
  int t = bid & 31;
  int mt = t & 3, ntile = t >> 2;
  int m0 = mt * 128, n0 = ntile * 128;
  const short* Ag = W + (size_t)m0 * 512;
  const short* Bg = XT + (size_t)b * HW_ * 512 + (size_t)n0 * 512;
  int lane = tid & 63, wave = tid >> 6;
  int wr = wave >> 1, wc = wave & 1;
  int mrow = wr * 64, ncol = wc * 64;
  int lrow = lane & 15;
  int slot = lane >> 4;          // 0..3 (16B k-slot within 64B row)

  f32x4 acc[4][4];
#pragma unroll
  for (int i = 0; i < 4; ++i)
#pragma unroll
    for (int j = 0; j < 4; ++j) acc[i][j] = (f32x4){0.f, 0.f, 0.f, 0.f};

  // STAGE(buf, k0): 8KB A-tile + 8KB B-tile, LDS linear dest, source slot-swizzled
  // (involution: LDS[row][s] = G[row][s ^ ((row>>1)&3)], 16B granular)
#define STAGE(bufidx, k0)                                                       \
  {                                                                             \
    _Pragma("unroll")                                                           \
    for (int it_ = 0; it_ < 2; ++it_) {                                         \
      int s_ = it_ * 256 + tid;                                                 \
      int L_ = s_ * 16;                                                         \
      int row_ = L_ >> 6;                                                       \
      int srcb_ = (L_ & 63) ^ (((row_ >> 1) & 3) << 4);                         \
      gload_lds16(Ag + (size_t)row_ * 512 + (k0) + (srcb_ >> 1),                \
                  smem + (bufidx) * 8192 + L_);                                 \
      gload_lds16(Bg + (size_t)row_ * 512 + (k0) + (srcb_ >> 1),                \
                  smem + 32768 + (bufidx) * 8192 + L_);                         \
    }                                                                           \
  }

  // STEP(KT, VN): wait stage KT (counted), barrier, prefetch KT+3, compute KT.
#define STEP(KT, VN)                                                            \
  {                                                                             \
    asm volatile("s_waitcnt vmcnt(" #VN ")" ::: "memory");                      \
    __builtin_amdgcn_s_barrier();                                               \
    if ((KT) + 3 < 16) STAGE(((KT) + 3) & 3, ((KT) + 3) * 32)                   \
    const char* Ab = smem + ((KT) & 3) * 8192;                                  \
    const char* Bb = smem + 32768 + ((KT) & 3) * 8192;                          \
    short8 af[4], bfv[4];                                                       \
    _Pragma("unroll")                                                           \
    for (int f = 0; f < 4; ++f) {                                               \
      int rowA = mrow + f * 16 + lrow;                                          \
      af[f] = *(const short8*)(Ab + rowA * 64 + (slot ^ ((rowA >> 1) & 3)) * 16);\
      int rowB = ncol + f * 16 + lrow;                                          \
      bfv[f] = *(const short8*)(Bb + rowB * 64 + (slot ^ ((rowB >> 1) & 3)) * 16);\
    }                                                                           \
    _Pragma("unroll")                                                           \
    for (int mf = 0; mf < 4; ++mf)                                              \
      _Pragma("unroll")                                                         \
      for (int nf = 0; nf < 4; ++nf)                                            \
        acc[mf][nf] = __builtin_amdgcn_mfma_f32_16x16x32_bf16(af[mf], bfv[nf],  \
                                                              acc[mf][nf], 0, 0, 0); \
  }

  // prologue: 3 stages in flight (12 loads)
  STAGE(0, 0)
  STAGE(1, 32)
  STAGE(2, 64)

  STEP(0, 8)  STEP(1, 8)  STEP(2, 8)  STEP(3, 8)
  STEP(4, 8)  STEP(5, 8)  STEP(6, 8)  STEP(7, 8)
  STEP(8, 8)  STEP(9, 8)  STEP(10, 8) STEP(11, 8)
  STEP(12, 8) STEP(13, 8) STEP(14, 4) STEP(15, 0)

  // epilogue: direct stores
  float* outb = out + (size_t)b * CO_ * HW_;
#pragma unroll
  for (int mf = 0; mf < 4; ++mf) {
#pragma unroll
    for (int j = 0; j < 4; ++j) {
      int o = m0 + mrow + mf * 16 + (lane >> 4) * 4 + j;   // C/D: row=(lane>>4)*4+reg
      float s = bs[o], bv = bb[o];
#pragma unroll
      for (int nf = 0; nf < 4; ++nf) {
        int p = n0 + ncol + nf * 16 + lrow;                // C/D: col=lane&15
        outb[(size_t)o * HW_ + p] = acc[mf][nf][j] * s + bv;
      }
    }
  }
#undef STEP
#undef STAGE
}

// ---------------- hada: fused per-pair stats + normalized product write ----------------
__global__ __launch_bounds__(256) void hada_kernel(
    const int* __restrict__ idx, const float* __restrict__ bn_gamma,
    const float* __restrict__ bn_beta, float* __restrict__ out) {
  int e = blockIdx.x, tid = threadIdx.x;
  int lane = tid & 63, wave = tid >> 6;
  // pair (i<j) from linear index e
  int i = 0, rem = e;
  while (rem >= 31 - i) { rem -= 31 - i; ++i; }
  int j = i + 1 + rem;

  __shared__ int chi[16], chj[16];
  if (tid < 16) chi[tid] = idx[tid * CS_ + i];
  else if (tid < 32) chj[tid - 16] = idx[(tid - 16) * CS_ + j];
  __syncthreads();

  f32x4 p[16];
  float s = 0.f, s2 = 0.f;
#pragma unroll
  for (int b = 0; b < 16; ++b) {
    const float4* xi = (const float4*)(out + ((size_t)b * CO_ + chi[b]) * HW_);
    const float4* xj = (const float4*)(out + ((size_t)b * CO_ + chj[b]) * HW_);
    float4 a = xi[tid], c = xj[tid];
    p[b][0] = a.x * c.x; p[b][1] = a.y * c.y; p[b][2] = a.z * c.z; p[b][3] = a.w * c.w;
    s  += p[b][0] + p[b][1] + p[b][2] + p[b][3];
    s2 += p[b][0]*p[b][0] + p[b][1]*p[b][1] + p[b][2]*p[b][2] + p[b][3]*p[b][3];
  }
  for (int off = 32; off; off >>= 1) { s += __shfl_down(s, off); s2 += __shfl_down(s2, off); }
  __shared__ float red[8];
  if (lane == 0) { red[wave] = s; red[4 + wave] = s2; }
  __syncthreads();
  float S  = red[0] + red[1] + red[2] + red[3];
  float S2 = red[4] + red[5] + red[6] + red[7];
  float mean = S * (1.f / 16384.f);
  float var  = S2 * (1.f / 16384.f) - mean * mean;
  float sc = (bn_gamma[i] * bn_gamma[j]) / sqrtf(var + 1e-5f);
  float bi_ = bn_beta[i] * bn_beta[j] - mean * sc;

#pragma unroll
  for (int b = 0; b < 16; ++b) {
    float4 r;
    r.x = p[b][0] * sc + bi_;
    r.y = p[b][1] * sc + bi_;
    r.z = p[b][2] * sc + bi_;
    r.w = p[b][3] * sc + bi_;
    ((float4*)(out + ((size_t)b * CO_ + C1_ + e) * HW_))[tid] = r;
  }
}

// ---------------- workspace layout (bytes) ----------------
#define XT_OFF     ((size_t)0)          // 16*1024*512*2 = 16777216
#define WBF_OFF    ((size_t)16777216)   // 524288
#define PART_OFF   ((size_t)17301504)   // 524288
#define PB_OFF     ((size_t)17825792)   // 32768
#define LOG_OFF    ((size_t)17858560)   // 32768
#define IDX_OFF    ((size_t)17891328)   // 2048
#define BS_OFF     ((size_t)17893376)   // 2048
#define BB_OFF     ((size_t)17895424)   // 2048

extern "C" void kernel_launch(void* const* d_in, const int* in_sizes, int n_in,
                              void* d_out, int out_size, void* d_ws, size_t ws_size,
                              hipStream_t stream) {
  const float* x        = (const float*)d_in[0];
  const float* fc_w     = (const float*)d_in[1];
  const float* fc_b     = (const float*)d_in[2];
  const float* bn_gamma = (const float*)d_in[3];
  const float* bn_beta  = (const float*)d_in[4];
  const float* bn_mean  = (const float*)d_in[5];
  const float* bn_var   = (const float*)d_in[6];
  const float* eva_w    = (const float*)d_in[7];
  const float* eva_b    = (const float*)d_in[8];
  float* out = (float*)d_out;
  char* ws = (char*)d_ws;

  short* xT      = (short*)(ws + XT_OFF);
  short* wbf     = (short*)(ws + WBF_OFF);
  float* partial = (float*)(ws + PART_OFF);
  float* pb      = (float*)(ws + PB_OFF);
  float* logits  = (float*)(ws + LOG_OFF);
  int*   idx     = (int*)(ws + IDX_OFF);
  float* bs      = (float*)(ws + BS_OFF);
  float* bb      = (float*)(ws + BB_OFF);

  hipLaunchKernelGGL(transpose_pool, dim3(3073), dim3(256), 0, stream,
                     x, xT, partial, fc_w, fc_b, bn_gamma, bn_beta, bn_mean, bn_var,
                     wbf, bs, bb);
  hipLaunchKernelGGL(gemm_kernel, dim3(640), dim3(256), 0, stream,
                     wbf, xT, bs, bb, out, partial, fc_w, pb);
  hipLaunchKernelGGL(eva_kernel, dim3(128), dim3(64), 0, stream,
                     pb, eva_w, eva_b, logits);
  hipLaunchKernelGGL(topk_kernel, dim3(16), dim3(64), 0, stream, logits, idx);
  hipLaunchKernelGGL(hada_kernel, dim3(CE_), dim3(256), 0, stream,
                     idx, bn_gamma, bn_beta, out);
}